// Round 1
// baseline (1344.573 us; speedup 1.0000x reference)
//
#include <hip/hip_runtime.h>

#define NUSERS 100000
#define NITEMS 50000
#define NTOT   150000   // NUSERS + NITEMS
#define DIM    64
#define NNZ    2000000
#define NLAYERS 3

// ---------------------------------------------------------------------------
// init: cur = concat(user_emb, item_emb); acc = 0.25 * cur
// ---------------------------------------------------------------------------
__global__ void lg_init(const float* __restrict__ ue, const float* __restrict__ ie,
                        float* __restrict__ cur, float* __restrict__ acc) {
    const long long total4 = (long long)NTOT * DIM / 4;
    const long long ubound4 = (long long)NUSERS * DIM / 4;
    const float4* ue4 = (const float4*)ue;
    const float4* ie4 = (const float4*)ie;
    float4* cur4 = (float4*)cur;
    float4* acc4 = (float4*)acc;
    for (long long i = blockIdx.x * (long long)blockDim.x + threadIdx.x; i < total4;
         i += (long long)gridDim.x * blockDim.x) {
        float4 v = (i < ubound4) ? ue4[i] : ie4[i - ubound4];
        cur4[i] = v;
        float4 a;
        a.x = 0.25f * v.x; a.y = 0.25f * v.y; a.z = 0.25f * v.z; a.w = 0.25f * v.w;
        acc4[i] = a;
    }
}

// ---------------------------------------------------------------------------
// scatter: one lane per (edge, dim). Wave = one edge: coalesced 256B gather of
// cur[col[e]*64 .. +63], scaled by vals[e], atomicAdd into next[row[e]*64+lane].
// ---------------------------------------------------------------------------
__global__ void lg_scatter(const float* __restrict__ cur, const float* __restrict__ vals,
                           const int* __restrict__ row, const int* __restrict__ col,
                           float* __restrict__ next) {
    const long long total = (long long)NNZ * 64;
    for (long long t = blockIdx.x * (long long)blockDim.x + threadIdx.x; t < total;
         t += (long long)gridDim.x * blockDim.x) {
        const int e    = (int)(t >> 6);
        const int lane = (int)(t & 63);
        const float v  = vals[e];          // wave-uniform broadcast
        const int   c  = col[e];
        const int   r  = row[e];
        const float m  = cur[(long long)c * DIM + lane] * v;
        atomicAdd(&next[(long long)r * DIM + lane], m);
    }
}

// ---------------------------------------------------------------------------
// axpy: acc += 0.25 * next
// ---------------------------------------------------------------------------
__global__ void lg_axpy(const float* __restrict__ next, float* __restrict__ acc) {
    const long long total4 = (long long)NTOT * DIM / 4;
    const float4* n4 = (const float4*)next;
    float4* a4 = (float4*)acc;
    for (long long i = blockIdx.x * (long long)blockDim.x + threadIdx.x; i < total4;
         i += (long long)gridDim.x * blockDim.x) {
        float4 n = n4[i];
        float4 a = a4[i];
        a.x += 0.25f * n.x; a.y += 0.25f * n.y; a.z += 0.25f * n.z; a.w += 0.25f * n.w;
        a4[i] = a;
    }
}

extern "C" void kernel_launch(void* const* d_in, const int* in_sizes, int n_in,
                              void* d_out, int out_size, void* d_ws, size_t ws_size,
                              hipStream_t stream) {
    const float* ue   = (const float*)d_in[0];   // user_emb  (100000 x 64)
    const float* ie   = (const float*)d_in[1];   // item_emb  (50000 x 64)
    const float* vals = (const float*)d_in[2];   // (2M)
    const int*   row  = (const int*)d_in[3];     // (2M)
    const int*   col  = (const int*)d_in[4];     // (2M)

    float* acc  = (float*)d_out;                 // 150000*64 fp32 = output
    float* buf0 = (float*)d_ws;                  // ping
    float* buf1 = buf0 + (size_t)NTOT * DIM;     // pong
    const size_t buf_bytes = (size_t)NTOT * DIM * sizeof(float);

    lg_init<<<2048, 256, 0, stream>>>(ue, ie, buf0, acc);

    float* cur = buf0;
    float* nxt = buf1;
    for (int l = 0; l < NLAYERS; ++l) {
        hipMemsetAsync(nxt, 0, buf_bytes, stream);
        lg_scatter<<<8192, 256, 0, stream>>>(cur, vals, row, col, nxt);
        lg_axpy<<<2048, 256, 0, stream>>>(nxt, acc);
        float* t = cur; cur = nxt; nxt = t;
    }
}

// Round 2
// 981.662 us; speedup vs baseline: 1.3697x; 1.3697x over previous
//
#include <hip/hip_runtime.h>

#define NUSERS 100000
#define NITEMS 50000
#define NTOT   150000   // NUSERS + NITEMS
#define DIM    64
#define NNZ    2000000
#define NLAYERS 3

// ---------------------------------------------------------------------------
// init: cur = concat(user_emb, item_emb); acc = 0.25 * cur
// ---------------------------------------------------------------------------
__global__ void lg_init(const float* __restrict__ ue, const float* __restrict__ ie,
                        float* __restrict__ cur, float* __restrict__ acc) {
    const int total4 = NTOT * DIM / 4;          // 2.4M
    const int ubound4 = NUSERS * DIM / 4;
    const float4* ue4 = (const float4*)ue;
    const float4* ie4 = (const float4*)ie;
    float4* cur4 = (float4*)cur;
    float4* acc4 = (float4*)acc;
    for (int i = blockIdx.x * blockDim.x + threadIdx.x; i < total4;
         i += gridDim.x * blockDim.x) {
        float4 v = (i < ubound4) ? ue4[i] : ie4[i - ubound4];
        cur4[i] = v;
        float4 a;
        a.x = 0.25f * v.x; a.y = 0.25f * v.y; a.z = 0.25f * v.z; a.w = 0.25f * v.w;
        acc4[i] = a;
    }
}

// ---------------------------------------------------------------------------
// CSR build step 1: row-degree histogram (deg must be pre-zeroed)
// ---------------------------------------------------------------------------
__global__ void lg_hist(const int* __restrict__ row, int* __restrict__ deg) {
    for (int e = blockIdx.x * blockDim.x + threadIdx.x; e < NNZ;
         e += gridDim.x * blockDim.x)
        atomicAdd(&deg[row[e]], 1);
}

// ---------------------------------------------------------------------------
// CSR build step 2: exclusive scan of deg -> ptr[0..NTOT], cursor = copy.
// Single block of 1024 threads, 147 elements each, Hillis-Steele block scan.
// ---------------------------------------------------------------------------
__global__ __launch_bounds__(1024) void lg_scan(const int* __restrict__ deg,
                                                int* __restrict__ ptr,
                                                int* __restrict__ cursor) {
    __shared__ int sums[1024];
    const int tid = threadIdx.x;
    const int CH = (NTOT + 1023) / 1024;        // 147
    const int beg = tid * CH;
    const int end = (beg + CH < NTOT) ? (beg + CH) : NTOT;
    int s = 0;
    for (int i = beg; i < end; ++i) s += deg[i];
    sums[tid] = s;
    __syncthreads();
    for (int off = 1; off < 1024; off <<= 1) {
        int t = (tid >= off) ? sums[tid - off] : 0;
        __syncthreads();
        sums[tid] += t;
        __syncthreads();
    }
    int run = sums[tid] - s;                    // exclusive prefix of my chunk
    for (int i = beg; i < end; ++i) {
        ptr[i] = run;
        cursor[i] = run;
        run += deg[i];
    }
    if (tid == 1023) ptr[NTOT] = run;           // total = NNZ
}

// ---------------------------------------------------------------------------
// CSR build step 3: scatter edges into their row segments, packed (col, val)
// ---------------------------------------------------------------------------
__global__ void lg_fill(const int* __restrict__ row, const int* __restrict__ col,
                        const float* __restrict__ vals, int* __restrict__ cursor,
                        int2* __restrict__ cedge) {
    for (int e = blockIdx.x * blockDim.x + threadIdx.x; e < NNZ;
         e += gridDim.x * blockDim.x) {
        const int r = row[e];
        const int slot = atomicAdd(&cursor[r], 1);
        cedge[slot] = make_int2(col[e], __float_as_int(vals[e]));
    }
}

// ---------------------------------------------------------------------------
// Propagation layer as a gather: one wave per row, lane = dim.
// next[r] = sum_e val[e]*cur[col[e]];  acc[r] += 0.25*next[r]
// ---------------------------------------------------------------------------
template<bool WRITE_NEXT>
__global__ void lg_gather(const int* __restrict__ ptr, const int2* __restrict__ cedge,
                          const float* __restrict__ cur, float* __restrict__ next,
                          float* __restrict__ acc) {
    const int gid = blockIdx.x * blockDim.x + threadIdx.x;
    const int r = gid >> 6;
    const int lane = gid & 63;
    if (r >= NTOT) return;
    const int beg = ptr[r];
    const int end = ptr[r + 1];
    float sum = 0.0f;
    int e = beg;
    for (; e + 1 < end; e += 2) {               // 2-way unroll: 2 gathers in flight
        const int2 c0 = cedge[e];
        const int2 c1 = cedge[e + 1];
        sum += __int_as_float(c0.y) * cur[c0.x * DIM + lane];
        sum += __int_as_float(c1.y) * cur[c1.x * DIM + lane];
    }
    if (e < end) {
        const int2 c0 = cedge[e];
        sum += __int_as_float(c0.y) * cur[c0.x * DIM + lane];
    }
    const int o = r * DIM + lane;
    if (WRITE_NEXT) next[o] = sum;
    acc[o] += 0.25f * sum;
}

// ---------------------------------------------------------------------------
// Fallback (round-1) kernels: edge-parallel scatter with atomics
// ---------------------------------------------------------------------------
__global__ void lg_scatter(const float* __restrict__ cur, const float* __restrict__ vals,
                           const int* __restrict__ row, const int* __restrict__ col,
                           float* __restrict__ next) {
    const long long total = (long long)NNZ * 64;
    for (long long t = blockIdx.x * (long long)blockDim.x + threadIdx.x; t < total;
         t += (long long)gridDim.x * blockDim.x) {
        const int e    = (int)(t >> 6);
        const int lane = (int)(t & 63);
        const float v  = vals[e];
        const int   c  = col[e];
        const int   r  = row[e];
        const float m  = cur[(long long)c * DIM + lane] * v;
        atomicAdd(&next[(long long)r * DIM + lane], m);
    }
}

__global__ void lg_axpy(const float* __restrict__ next, float* __restrict__ acc) {
    const int total4 = NTOT * DIM / 4;
    const float4* n4 = (const float4*)next;
    float4* a4 = (float4*)acc;
    for (int i = blockIdx.x * blockDim.x + threadIdx.x; i < total4;
         i += gridDim.x * blockDim.x) {
        float4 n = n4[i];
        float4 a = a4[i];
        a.x += 0.25f * n.x; a.y += 0.25f * n.y; a.z += 0.25f * n.z; a.w += 0.25f * n.w;
        a4[i] = a;
    }
}

extern "C" void kernel_launch(void* const* d_in, const int* in_sizes, int n_in,
                              void* d_out, int out_size, void* d_ws, size_t ws_size,
                              hipStream_t stream) {
    const float* ue   = (const float*)d_in[0];   // user_emb  (100000 x 64)
    const float* ie   = (const float*)d_in[1];   // item_emb  (50000 x 64)
    const float* vals = (const float*)d_in[2];   // (2M)
    const int*   row  = (const int*)d_in[3];     // (2M)
    const int*   col  = (const int*)d_in[4];     // (2M)

    float* acc = (float*)d_out;                  // 150000*64 fp32 = output

    const size_t EMB = (size_t)NTOT * DIM;       // 9.6M floats
    float* buf0   = (float*)d_ws;                // ping
    float* buf1   = buf0 + EMB;                  // pong
    int*   ptr    = (int*)(buf1 + EMB);          // NTOT+1
    int*   cursor = ptr + (NTOT + 1);            // NTOT
    int*   deg    = cursor + NTOT;               // NTOT (+1 pad for int2 alignment)
    int2*  cedge  = (int2*)(deg + NTOT + 1);     // NNZ packed (col, val)

    const size_t need = 2 * EMB * sizeof(float)
                      + ((size_t)3 * NTOT + 2) * sizeof(int)
                      + (size_t)NNZ * sizeof(int2);   // ~94.6 MB

    if (ws_size >= need) {
        // ---- CSR-gather path ----
        lg_init<<<1024, 256, 0, stream>>>(ue, ie, buf0, acc);
        hipMemsetAsync(deg, 0, NTOT * sizeof(int), stream);
        lg_hist<<<2048, 256, 0, stream>>>(row, deg);
        lg_scan<<<1, 1024, 0, stream>>>(deg, ptr, cursor);
        lg_fill<<<2048, 256, 0, stream>>>(row, col, vals, cursor, cedge);

        const int gblocks = (NTOT * DIM) / 256;  // 37500, exact
        lg_gather<true ><<<gblocks, 256, 0, stream>>>(ptr, cedge, buf0, buf1, acc);
        lg_gather<true ><<<gblocks, 256, 0, stream>>>(ptr, cedge, buf1, buf0, acc);
        lg_gather<false><<<gblocks, 256, 0, stream>>>(ptr, cedge, buf0, nullptr, acc);
    } else {
        // ---- fallback: round-1 scatter path (needs only the two ping-pong bufs) ----
        const size_t buf_bytes = EMB * sizeof(float);
        lg_init<<<1024, 256, 0, stream>>>(ue, ie, buf0, acc);
        float* cur = buf0;
        float* nxt = buf1;
        for (int l = 0; l < NLAYERS; ++l) {
            hipMemsetAsync(nxt, 0, buf_bytes, stream);
            lg_scatter<<<8192, 256, 0, stream>>>(cur, vals, row, col, nxt);
            lg_axpy<<<1024, 256, 0, stream>>>(nxt, acc);
            float* t = cur; cur = nxt; nxt = t;
        }
    }
}

// Round 3
// 566.155 us; speedup vs baseline: 2.3749x; 1.7339x over previous
//
#include <hip/hip_runtime.h>

#define NUSERS 100000
#define NITEMS 50000
#define NTOT   150000   // NUSERS + NITEMS
#define DIM    64
#define NNZ    2000000
#define NLAYERS 3

// ---------------------------------------------------------------------------
// init (3-buffer path): cur = concat(user_emb, item_emb)
// ---------------------------------------------------------------------------
__global__ void lg_init3(const float* __restrict__ ue, const float* __restrict__ ie,
                         float* __restrict__ cur) {
    const int total4 = NTOT * DIM / 4;
    const int ubound4 = NUSERS * DIM / 4;
    const float4* ue4 = (const float4*)ue;
    const float4* ie4 = (const float4*)ie;
    float4* cur4 = (float4*)cur;
    for (int i = blockIdx.x * blockDim.x + threadIdx.x; i < total4;
         i += gridDim.x * blockDim.x)
        cur4[i] = (i < ubound4) ? ue4[i] : ie4[i - ubound4];
}

// init (2-buffer path): cur = concat; acc = 0.25*cur
__global__ void lg_init2(const float* __restrict__ ue, const float* __restrict__ ie,
                         float* __restrict__ cur, float* __restrict__ acc) {
    const int total4 = NTOT * DIM / 4;
    const int ubound4 = NUSERS * DIM / 4;
    const float4* ue4 = (const float4*)ue;
    const float4* ie4 = (const float4*)ie;
    float4* cur4 = (float4*)cur;
    float4* acc4 = (float4*)acc;
    for (int i = blockIdx.x * blockDim.x + threadIdx.x; i < total4;
         i += gridDim.x * blockDim.x) {
        float4 v = (i < ubound4) ? ue4[i] : ie4[i - ubound4];
        cur4[i] = v;
        float4 a;
        a.x = 0.25f * v.x; a.y = 0.25f * v.y; a.z = 0.25f * v.z; a.w = 0.25f * v.w;
        acc4[i] = a;
    }
}

// ---------------------------------------------------------------------------
// CSR build step 1: row-degree histogram (deg pre-zeroed)
// ---------------------------------------------------------------------------
__global__ void lg_hist(const int* __restrict__ row, int* __restrict__ deg) {
    for (int e = blockIdx.x * blockDim.x + threadIdx.x; e < NNZ;
         e += gridDim.x * blockDim.x)
        atomicAdd(&deg[row[e]], 1);
}

// ---------------------------------------------------------------------------
// CSR build step 2: segment allocation WITHOUT a scan.
// Wave-aggregated bump allocator: 64-lane shuffle prefix of degrees,
// one atomicAdd on a global counter per wave. Segment order is arbitrary
// (not row-sorted) — gather only needs disjoint [beg, end) per row.
// ---------------------------------------------------------------------------
__global__ void lg_alloc(const int* __restrict__ deg, int* __restrict__ beg,
                         int* __restrict__ cursor, int* __restrict__ cnt) {
    const int r = blockIdx.x * blockDim.x + threadIdx.x;
    const int lane = threadIdx.x & 63;
    const int d = (r < NTOT) ? deg[r] : 0;
    int incl = d;                                 // inclusive wave prefix sum
    #pragma unroll
    for (int off = 1; off < 64; off <<= 1) {
        int t = __shfl_up(incl, off, 64);
        if (lane >= off) incl += t;
    }
    int base = 0;
    if (lane == 63) base = atomicAdd(cnt, incl);  // incl@63 == wave total
    base = __shfl(base, 63, 64);
    if (r < NTOT) {
        const int b = base + incl - d;
        beg[r] = b;
        cursor[r] = b;
    }
}

// ---------------------------------------------------------------------------
// CSR build step 3: scatter edges into their row segments, packed (col, val)
// After this, cursor[r] == segment end for row r.
// ---------------------------------------------------------------------------
__global__ void lg_fill(const int* __restrict__ row, const int* __restrict__ col,
                        const float* __restrict__ vals, int* __restrict__ cursor,
                        int2* __restrict__ cedge) {
    for (int e = blockIdx.x * blockDim.x + threadIdx.x; e < NNZ;
         e += gridDim.x * blockDim.x) {
        const int r = row[e];
        const int slot = atomicAdd(&cursor[r], 1);
        cedge[slot] = make_int2(col[e], __float_as_int(vals[e]));
    }
}

// ---------------------------------------------------------------------------
// Gather layer: one wave per row, lane = dim, 4-way edge unroll.
// ---------------------------------------------------------------------------
__device__ __forceinline__ float row_gather(const int* __restrict__ beg_,
                                            const int* __restrict__ end_,
                                            const int2* __restrict__ cedge,
                                            const float* __restrict__ cur,
                                            int r, int lane) {
    int e = beg_[r];
    const int end = end_[r];
    float sum = 0.0f;
    for (; e + 3 < end; e += 4) {
        const int2 c0 = cedge[e];
        const int2 c1 = cedge[e + 1];
        const int2 c2 = cedge[e + 2];
        const int2 c3 = cedge[e + 3];
        sum += __int_as_float(c0.y) * cur[c0.x * DIM + lane];
        sum += __int_as_float(c1.y) * cur[c1.x * DIM + lane];
        sum += __int_as_float(c2.y) * cur[c2.x * DIM + lane];
        sum += __int_as_float(c3.y) * cur[c3.x * DIM + lane];
    }
    for (; e < end; ++e) {
        const int2 c = cedge[e];
        sum += __int_as_float(c.y) * cur[c.x * DIM + lane];
    }
    return sum;
}

// mid layer: next = A*cur
__global__ void lg_gather_mid(const int* __restrict__ beg_, const int* __restrict__ end_,
                              const int2* __restrict__ cedge,
                              const float* __restrict__ cur, float* __restrict__ next) {
    const int gid = blockIdx.x * blockDim.x + threadIdx.x;
    const int r = gid >> 6, lane = gid & 63;
    if (r >= NTOT) return;
    next[r * DIM + lane] = row_gather(beg_, end_, cedge, cur, r, lane);
}

// last layer, fused combine: acc = 0.25*(e0 + e1 + e2 + A*e2rows)
__global__ void lg_gather_last(const int* __restrict__ beg_, const int* __restrict__ end_,
                               const int2* __restrict__ cedge,
                               const float* __restrict__ b0, const float* __restrict__ b1,
                               const float* __restrict__ b2, float* __restrict__ acc) {
    const int gid = blockIdx.x * blockDim.x + threadIdx.x;
    const int r = gid >> 6, lane = gid & 63;
    if (r >= NTOT) return;
    const float sum = row_gather(beg_, end_, cedge, b2, r, lane);
    const int o = r * DIM + lane;
    acc[o] = 0.25f * (b0[o] + b1[o] + b2[o] + sum);
}

// 2-buffer path: next = A*cur (optional), acc += 0.25*sum
template<bool WRITE_NEXT>
__global__ void lg_gather_acc(const int* __restrict__ beg_, const int* __restrict__ end_,
                              const int2* __restrict__ cedge,
                              const float* __restrict__ cur, float* __restrict__ next,
                              float* __restrict__ acc) {
    const int gid = blockIdx.x * blockDim.x + threadIdx.x;
    const int r = gid >> 6, lane = gid & 63;
    if (r >= NTOT) return;
    const float sum = row_gather(beg_, end_, cedge, cur, r, lane);
    const int o = r * DIM + lane;
    if (WRITE_NEXT) next[o] = sum;
    acc[o] += 0.25f * sum;
}

// ---------------------------------------------------------------------------
// Fallback (round-1) kernels: edge-parallel scatter with atomics
// ---------------------------------------------------------------------------
__global__ void lg_scatter(const float* __restrict__ cur, const float* __restrict__ vals,
                           const int* __restrict__ row, const int* __restrict__ col,
                           float* __restrict__ next) {
    const long long total = (long long)NNZ * 64;
    for (long long t = blockIdx.x * (long long)blockDim.x + threadIdx.x; t < total;
         t += (long long)gridDim.x * blockDim.x) {
        const int e    = (int)(t >> 6);
        const int lane = (int)(t & 63);
        const float m  = cur[(long long)col[e] * DIM + lane] * vals[e];
        atomicAdd(&next[(long long)row[e] * DIM + lane], m);
    }
}

__global__ void lg_axpy(const float* __restrict__ next, float* __restrict__ acc) {
    const int total4 = NTOT * DIM / 4;
    const float4* n4 = (const float4*)next;
    float4* a4 = (float4*)acc;
    for (int i = blockIdx.x * blockDim.x + threadIdx.x; i < total4;
         i += gridDim.x * blockDim.x) {
        float4 n = n4[i];
        float4 a = a4[i];
        a.x += 0.25f * n.x; a.y += 0.25f * n.y; a.z += 0.25f * n.z; a.w += 0.25f * n.w;
        a4[i] = a;
    }
}

extern "C" void kernel_launch(void* const* d_in, const int* in_sizes, int n_in,
                              void* d_out, int out_size, void* d_ws, size_t ws_size,
                              hipStream_t stream) {
    const float* ue   = (const float*)d_in[0];   // user_emb  (100000 x 64)
    const float* ie   = (const float*)d_in[1];   // item_emb  (50000 x 64)
    const float* vals = (const float*)d_in[2];   // (2M)
    const int*   row  = (const int*)d_in[3];     // (2M)
    const int*   col  = (const int*)d_in[4];     // (2M)

    float* acc = (float*)d_out;                  // 150000*64 fp32 = output

    const size_t EMB = (size_t)NTOT * DIM;       // 9.6M floats
    const size_t INTS = (size_t)3 * NTOT + 2;    // beg, cursor, deg, cnt, pad (even)
    const size_t need3 = 3 * EMB * sizeof(float) + INTS * sizeof(int) + (size_t)NNZ * sizeof(int2);
    const size_t need2 = 2 * EMB * sizeof(float) + INTS * sizeof(int) + (size_t)NNZ * sizeof(int2);

    const int ablocks = (NTOT + 255) / 256;      // 586  (alloc)
    const int gblocks = (NTOT * DIM) / 256;      // 37500 (gather, exact)

    if (ws_size >= need3) {
        // ---- 3-buffer fused path ----
        float* b0     = (float*)d_ws;            // layer-0 (embeddings)
        float* b1     = b0 + EMB;                // layer-1 output
        float* b2     = b1 + EMB;                // layer-2 output
        int*   beg    = (int*)(b2 + EMB);
        int*   cursor = beg + NTOT;
        int*   deg    = cursor + NTOT;           // deg[NTOT] then cnt[1]
        int*   cnt    = deg + NTOT;
        int2*  cedge  = (int2*)(cnt + 2);        // 8B-aligned (INTS even)

        lg_init3<<<1024, 256, 0, stream>>>(ue, ie, b0);
        hipMemsetAsync(deg, 0, (NTOT + 1) * sizeof(int), stream);  // deg + cnt
        lg_hist<<<2048, 256, 0, stream>>>(row, deg);
        lg_alloc<<<ablocks, 256, 0, stream>>>(deg, beg, cursor, cnt);
        lg_fill<<<2048, 256, 0, stream>>>(row, col, vals, cursor, cedge);

        lg_gather_mid <<<gblocks, 256, 0, stream>>>(beg, cursor, cedge, b0, b1);
        lg_gather_mid <<<gblocks, 256, 0, stream>>>(beg, cursor, cedge, b1, b2);
        lg_gather_last<<<gblocks, 256, 0, stream>>>(beg, cursor, cedge, b0, b1, b2, acc);
    } else if (ws_size >= need2) {
        // ---- 2-buffer path (fast alloc, acc RMW) ----
        float* b0     = (float*)d_ws;
        float* b1     = b0 + EMB;
        int*   beg    = (int*)(b1 + EMB);
        int*   cursor = beg + NTOT;
        int*   deg    = cursor + NTOT;
        int*   cnt    = deg + NTOT;
        int2*  cedge  = (int2*)(cnt + 2);

        lg_init2<<<1024, 256, 0, stream>>>(ue, ie, b0, acc);
        hipMemsetAsync(deg, 0, (NTOT + 1) * sizeof(int), stream);
        lg_hist<<<2048, 256, 0, stream>>>(row, deg);
        lg_alloc<<<ablocks, 256, 0, stream>>>(deg, beg, cursor, cnt);
        lg_fill<<<2048, 256, 0, stream>>>(row, col, vals, cursor, cedge);

        lg_gather_acc<true ><<<gblocks, 256, 0, stream>>>(beg, cursor, cedge, b0, b1, acc);
        lg_gather_acc<true ><<<gblocks, 256, 0, stream>>>(beg, cursor, cedge, b1, b0, acc);
        lg_gather_acc<false><<<gblocks, 256, 0, stream>>>(beg, cursor, cedge, b0, nullptr, acc);
    } else {
        // ---- minimal fallback: round-1 scatter path ----
        const size_t buf_bytes = EMB * sizeof(float);
        float* cur = (float*)d_ws;
        float* nxt = cur + EMB;
        lg_init2<<<1024, 256, 0, stream>>>(ue, ie, cur, acc);
        for (int l = 0; l < NLAYERS; ++l) {
            hipMemsetAsync(nxt, 0, buf_bytes, stream);
            lg_scatter<<<8192, 256, 0, stream>>>(cur, vals, row, col, nxt);
            lg_axpy<<<1024, 256, 0, stream>>>(nxt, acc);
            float* t = cur; cur = nxt; nxt = t;
        }
    }
}

// Round 4
// 262.314 us; speedup vs baseline: 5.1258x; 2.1583x over previous
//
#include <hip/hip_runtime.h>
#include <hip/hip_fp16.h>

#define NUSERS 100000
#define NITEMS 50000
#define NTOT   150000   // NUSERS + NITEMS
#define DIM    64
#define NNZ    2000000
#define NLAYERS 3
#define NB     147      // buckets of 1024 rows: 147*1024 = 150528 >= NTOT
#define CHUNK  4096     // edges per partition block

// ---------------------------------------------------------------------------
// init: b0 = fp16(concat(user_emb, item_emb))  — 4 floats -> 4 halves / thread
// ---------------------------------------------------------------------------
__global__ void lg_inith(const float* __restrict__ ue, const float* __restrict__ ie,
                         __half* __restrict__ b0) {
    const int total4 = NTOT * DIM / 4;          // 2.4M float4-groups
    const int ubound4 = NUSERS * DIM / 4;
    const float4* ue4 = (const float4*)ue;
    const float4* ie4 = (const float4*)ie;
    uint2* out = (uint2*)b0;                    // 4 halves = 8B
    for (int i = blockIdx.x * blockDim.x + threadIdx.x; i < total4;
         i += gridDim.x * blockDim.x) {
        const float4 v = (i < ubound4) ? ue4[i] : ie4[i - ubound4];
        __half2 h0 = __floats2half2_rn(v.x, v.y);
        __half2 h1 = __floats2half2_rn(v.z, v.w);
        uint2 u;
        u.x = *(const unsigned int*)&h0;
        u.y = *(const unsigned int*)&h1;
        out[i] = u;
    }
}

// ---------------------------------------------------------------------------
// bucket histogram: bucket = row >> 10 (1024 rows/bucket). LDS hist, one
// global atomic per (block,bucket). bcnt pre-zeroed.
// ---------------------------------------------------------------------------
__global__ void lg_bhist(const int* __restrict__ row, int* __restrict__ bcnt) {
    __shared__ int h[NB];
    for (int i = threadIdx.x; i < NB; i += blockDim.x) h[i] = 0;
    __syncthreads();
    for (int e = blockIdx.x * blockDim.x + threadIdx.x; e < NNZ;
         e += gridDim.x * blockDim.x)
        atomicAdd(&h[row[e] >> 10], 1);
    __syncthreads();
    for (int i = threadIdx.x; i < NB; i += blockDim.x)
        if (h[i]) atomicAdd(&bcnt[i], h[i]);
}

// ---------------------------------------------------------------------------
// bucket scan: bptr[0..NB] exclusive ptr, bcur[b] = running cursor base
// ---------------------------------------------------------------------------
__global__ __launch_bounds__(256) void lg_bscan(const int* __restrict__ bcnt,
                                                int* __restrict__ bptr,
                                                int* __restrict__ bcur) {
    __shared__ int sc[256];
    const int t = threadIdx.x;
    const int own = (t < NB) ? bcnt[t] : 0;
    sc[t] = own;
    __syncthreads();
    for (int o = 1; o < 256; o <<= 1) {
        int v = (t >= o) ? sc[t - o] : 0;
        __syncthreads();
        sc[t] += v;
        __syncthreads();
    }
    if (t < NB) {
        bptr[t + 1] = sc[t];            // inclusive
        bcur[t] = sc[t] - own;          // exclusive base
    }
    if (t == 0) bptr[0] = 0;
}

// ---------------------------------------------------------------------------
// partition: chunk-aggregated scatter into bucket segments. Each block stages
// CHUNK edges in LDS grouped by bucket, claims each bucket run with ONE global
// atomic, flushes runs coalesced. tmp entry: ((row&1023)<<18 | col, val_f32).
// ---------------------------------------------------------------------------
__global__ __launch_bounds__(256) void lg_part(const int* __restrict__ row,
                                               const int* __restrict__ col,
                                               const float* __restrict__ vals,
                                               int* __restrict__ bcur,
                                               int2* __restrict__ tmp) {
    __shared__ int h[NB], off[NB], cnt2[NB], bs[NB];
    __shared__ int sc[256];
    __shared__ unsigned char bk[CHUNK];
    __shared__ int2 stag[CHUNK];
    const int t = threadIdx.x;
    const int e0 = blockIdx.x * CHUNK;
    const int n = (NNZ - e0 < CHUNK) ? (NNZ - e0) : CHUNK;

    for (int i = t; i < NB; i += 256) { h[i] = 0; cnt2[i] = 0; }
    __syncthreads();
    for (int i = t; i < n; i += 256)
        atomicAdd(&h[row[e0 + i] >> 10], 1);
    __syncthreads();
    // scan h (NB entries, padded to 256)
    const int own = (t < NB) ? h[t] : 0;
    sc[t] = own;
    __syncthreads();
    for (int o = 1; o < 256; o <<= 1) {
        int v = (t >= o) ? sc[t - o] : 0;
        __syncthreads();
        sc[t] += v;
        __syncthreads();
    }
    if (t < NB) off[t] = sc[t] - own;
    __syncthreads();
    // place into LDS staging grouped by bucket
    for (int i = t; i < n; i += 256) {
        const int e = e0 + i;
        const int r = row[e];
        const int b = r >> 10;
        const int k = atomicAdd(&cnt2[b], 1);
        const int s = off[b] + k;
        stag[s] = make_int2(((r & 1023) << 18) | col[e], __float_as_int(vals[e]));
        bk[s] = (unsigned char)b;
    }
    __syncthreads();
    // claim global runs (one atomic per present bucket)
    if (t < NB && own > 0) bs[t] = atomicAdd(&bcur[t], own);
    __syncthreads();
    // coalesced flush
    for (int s = t; s < n; s += 256) {
        const int b = bk[s];
        tmp[bs[b] + (s - off[b])] = stag[s];
    }
}

// ---------------------------------------------------------------------------
// rowsort: one block per bucket. LDS row-hist (1024 rows) + LDS scan -> per-row
// [beg,end) written to be[]; second pass scatters (col,val) into cedge within
// the bucket's contiguous (XCD-L2-resident) region.
// ---------------------------------------------------------------------------
__global__ __launch_bounds__(1024) void lg_rsort(const int2* __restrict__ tmp,
                                                 const int* __restrict__ bptr,
                                                 int2* __restrict__ be,
                                                 int2* __restrict__ cedge) {
    __shared__ int h[1024];
    const int b = blockIdx.x;
    const int t = threadIdx.x;
    const int s0 = bptr[b], s1 = bptr[b + 1];
    h[t] = 0;
    __syncthreads();
    for (int s = s0 + t; s < s1; s += 1024)
        atomicAdd(&h[(tmp[s].x >> 18) & 1023], 1);
    __syncthreads();
    const int own = h[t];
    // inclusive scan over 1024
    for (int o = 1; o < 1024; o <<= 1) {
        int v = (t >= o) ? h[t - o] : 0;
        __syncthreads();
        h[t] += v;
        __syncthreads();
    }
    const int excl = h[t] - own;
    const int r = (b << 10) + t;
    if (r < NTOT) be[r] = make_int2(s0 + excl, s0 + excl + own);
    __syncthreads();
    h[t] = excl;                        // reuse as cursor
    __syncthreads();
    for (int s = s0 + t; s < s1; s += 1024) {
        const int2 ev = tmp[s];
        const int rl = (ev.x >> 18) & 1023;
        const int k = atomicAdd(&h[rl], 1);
        cedge[s0 + k] = make_int2(ev.x & 0x3FFFF, ev.y);
    }
}

// ---------------------------------------------------------------------------
// gather core: wave = one row. 8 groups x 8 lanes; group g walks edges
// beg+g, beg+g+8, ...; lane loads 16B (8 fp16) of the source row; fp32
// accumulate; 3 shfl_xor steps reduce the 8 groups.
// ---------------------------------------------------------------------------
__device__ __forceinline__ void row_gather8(const int2* __restrict__ be,
                                            const int2* __restrict__ cedge,
                                            const __half* __restrict__ cur,
                                            int r, int lane, float sum[8]) {
    const int2 p = be[r];
    const int g = lane >> 3;
    const int d = lane & 7;
    #pragma unroll
    for (int k = 0; k < 8; ++k) sum[k] = 0.0f;
    for (int e = p.x + g; e < p.y; e += 8) {
        const int2 cv = cedge[e];
        const float v = __int_as_float(cv.y);
        const uint4 q = ((const uint4*)(cur + ((size_t)cv.x << 6)))[d];
        const __half2* hp = (const __half2*)&q;
        #pragma unroll
        for (int k = 0; k < 4; ++k) {
            const float2 f = __half22float2(hp[k]);
            sum[2 * k]     += v * f.x;
            sum[2 * k + 1] += v * f.y;
        }
    }
    #pragma unroll
    for (int m = 8; m < 64; m <<= 1) {
        #pragma unroll
        for (int k = 0; k < 8; ++k)
            sum[k] += __shfl_xor(sum[k], m, 64);
    }
}

// mid layer: nxt = fp16(A * cur)
__global__ void lg_gmid(const int2* __restrict__ be, const int2* __restrict__ cedge,
                        const __half* __restrict__ cur, __half* __restrict__ nxt) {
    const int gid = blockIdx.x * blockDim.x + threadIdx.x;
    const int r = gid >> 6, lane = gid & 63;
    if (r >= NTOT) return;
    float s[8];
    row_gather8(be, cedge, cur, r, lane, s);
    if ((lane >> 3) == 0) {
        __half2 o[4];
        #pragma unroll
        for (int k = 0; k < 4; ++k) o[k] = __floats2half2_rn(s[2 * k], s[2 * k + 1]);
        ((uint4*)(nxt + ((size_t)r << 6)))[lane & 7] = *(const uint4*)o;
    }
}

// last layer, fused: acc = 0.25*(b0 + b1 + b2 + A*b2)   (fp32 output)
__global__ void lg_glast(const int2* __restrict__ be, const int2* __restrict__ cedge,
                         const __half* __restrict__ b0, const __half* __restrict__ b1,
                         const __half* __restrict__ b2, float* __restrict__ acc) {
    const int gid = blockIdx.x * blockDim.x + threadIdx.x;
    const int r = gid >> 6, lane = gid & 63;
    if (r >= NTOT) return;
    float s[8];
    row_gather8(be, cedge, b2, r, lane, s);
    if ((lane >> 3) == 0) {
        const int d = lane & 7;
        const size_t base = (size_t)r << 6;
        const uint4 q0 = ((const uint4*)(b0 + base))[d];
        const uint4 q1 = ((const uint4*)(b1 + base))[d];
        const uint4 q2 = ((const uint4*)(b2 + base))[d];
        const __half2* h0 = (const __half2*)&q0;
        const __half2* h1 = (const __half2*)&q1;
        const __half2* h2 = (const __half2*)&q2;
        float out[8];
        #pragma unroll
        for (int k = 0; k < 4; ++k) {
            const float2 f0 = __half22float2(h0[k]);
            const float2 f1 = __half22float2(h1[k]);
            const float2 f2 = __half22float2(h2[k]);
            out[2 * k]     = 0.25f * (f0.x + f1.x + f2.x + s[2 * k]);
            out[2 * k + 1] = 0.25f * (f0.y + f1.y + f2.y + s[2 * k + 1]);
        }
        float4* dst = (float4*)(acc + base + (size_t)d * 8);
        dst[0] = make_float4(out[0], out[1], out[2], out[3]);
        dst[1] = make_float4(out[4], out[5], out[6], out[7]);
    }
}

// ---------------------------------------------------------------------------
// Fallback (round-1) kernels: edge-parallel scatter with fp32 atomics
// ---------------------------------------------------------------------------
__global__ void lg_init2(const float* __restrict__ ue, const float* __restrict__ ie,
                         float* __restrict__ cur, float* __restrict__ acc) {
    const int total4 = NTOT * DIM / 4;
    const int ubound4 = NUSERS * DIM / 4;
    const float4* ue4 = (const float4*)ue;
    const float4* ie4 = (const float4*)ie;
    float4* cur4 = (float4*)cur;
    float4* acc4 = (float4*)acc;
    for (int i = blockIdx.x * blockDim.x + threadIdx.x; i < total4;
         i += gridDim.x * blockDim.x) {
        float4 v = (i < ubound4) ? ue4[i] : ie4[i - ubound4];
        cur4[i] = v;
        float4 a;
        a.x = 0.25f * v.x; a.y = 0.25f * v.y; a.z = 0.25f * v.z; a.w = 0.25f * v.w;
        acc4[i] = a;
    }
}

__global__ void lg_scatter(const float* __restrict__ cur, const float* __restrict__ vals,
                           const int* __restrict__ row, const int* __restrict__ col,
                           float* __restrict__ next) {
    const long long total = (long long)NNZ * 64;
    for (long long t = blockIdx.x * (long long)blockDim.x + threadIdx.x; t < total;
         t += (long long)gridDim.x * blockDim.x) {
        const int e    = (int)(t >> 6);
        const int lane = (int)(t & 63);
        const float m  = cur[(long long)col[e] * DIM + lane] * vals[e];
        atomicAdd(&next[(long long)row[e] * DIM + lane], m);
    }
}

__global__ void lg_axpy(const float* __restrict__ next, float* __restrict__ acc) {
    const int total4 = NTOT * DIM / 4;
    const float4* n4 = (const float4*)next;
    float4* a4 = (float4*)acc;
    for (int i = blockIdx.x * blockDim.x + threadIdx.x; i < total4;
         i += gridDim.x * blockDim.x) {
        float4 n = n4[i];
        float4 a = a4[i];
        a.x += 0.25f * n.x; a.y += 0.25f * n.y; a.z += 0.25f * n.z; a.w += 0.25f * n.w;
        a4[i] = a;
    }
}

extern "C" void kernel_launch(void* const* d_in, const int* in_sizes, int n_in,
                              void* d_out, int out_size, void* d_ws, size_t ws_size,
                              hipStream_t stream) {
    const float* ue   = (const float*)d_in[0];
    const float* ie   = (const float*)d_in[1];
    const float* vals = (const float*)d_in[2];
    const int*   row  = (const int*)d_in[3];
    const int*   col  = (const int*)d_in[4];

    float* acc = (float*)d_out;

    const size_t EMB = (size_t)NTOT * DIM;       // 9.6M elements

    // workspace layout (fp16 path)
    __half* b0   = (__half*)d_ws;                // 19.2 MB
    __half* b1   = b0 + EMB;                     // 19.2 MB
    __half* b2   = b1 + EMB;                     // 19.2 MB
    int2* tmp    = (int2*)(b2 + EMB);            // 16 MB  (bucket-partitioned edges)
    int2* cedge  = tmp + NNZ;                    // 16 MB  (row-sorted (col,val))
    int2* be     = cedge + NNZ;                  // 1.2 MB (per-row [beg,end))
    int*  bcnt   = (int*)(be + NTOT);            // NB
    int*  bptr   = bcnt + NB;                    // NB+1
    int*  bcur   = bptr + NB + 1;                // NB
    const size_t need = (size_t)((char*)(bcur + NB) - (char*)d_ws);   // ~90.8 MB

    if (ws_size >= need) {
        const int nchunks = (NNZ + CHUNK - 1) / CHUNK;   // 489
        const int gblocks = (NTOT * DIM) / 256;          // 37500

        lg_inith<<<1024, 256, 0, stream>>>(ue, ie, b0);
        hipMemsetAsync(bcnt, 0, NB * sizeof(int), stream);
        lg_bhist<<<256, 256, 0, stream>>>(row, bcnt);
        lg_bscan<<<1, 256, 0, stream>>>(bcnt, bptr, bcur);
        lg_part<<<nchunks, 256, 0, stream>>>(row, col, vals, bcur, tmp);
        lg_rsort<<<NB, 1024, 0, stream>>>(tmp, bptr, be, cedge);

        lg_gmid <<<gblocks, 256, 0, stream>>>(be, cedge, b0, b1);
        lg_gmid <<<gblocks, 256, 0, stream>>>(be, cedge, b1, b2);
        lg_glast<<<gblocks, 256, 0, stream>>>(be, cedge, b0, b1, b2, acc);
    } else {
        // minimal fallback: round-1 scatter path (2 x 38.4 MB fp32)
        float* cur = (float*)d_ws;
        float* nxt = cur + EMB;
        const size_t buf_bytes = EMB * sizeof(float);
        lg_init2<<<1024, 256, 0, stream>>>(ue, ie, cur, acc);
        for (int l = 0; l < NLAYERS; ++l) {
            hipMemsetAsync(nxt, 0, buf_bytes, stream);
            lg_scatter<<<8192, 256, 0, stream>>>(cur, vals, row, col, nxt);
            lg_axpy<<<1024, 256, 0, stream>>>(nxt, acc);
            float* t = cur; cur = nxt; nxt = t;
        }
    }
}